// Round 8
// baseline (86.920 us; speedup 1.0000x reference)
//
#include <hip/hip_runtime.h>
#include <hip/hip_bf16.h>

#define BATCH 64
#define SEQ 32
#define DIM 1024
#define EOUT 4096
#define NFW 16

#define BM 256   // rows per block tile (8 batch-slots x 32 seq)
#define BN 128   // cols per block tile
#define BK 64    // k chunk
#define XK 68    // XT row stride: 17 dwords, odd -> conflict-free b64 ops
#define WK 68    // WT row stride: same
#define MAX_ITEMS 22   // max sum ceil(cnt/8) with sum cnt = 64 over 16 fws
#define NXCD 8

typedef float  f32x4 __attribute__((ext_vector_type(4)));
typedef short  s16x4 __attribute__((ext_vector_type(4)));
typedef short  s16x8 __attribute__((ext_vector_type(8)));

__device__ __forceinline__ short f2bf(float f) {
    union { float f; unsigned u; } v; v.f = f;
    unsigned r = v.u + 0x7fffu + ((v.u >> 16) & 1u);   // RNE
    return (short)(r >> 16);
}

// ---- fused prep: X fp32->bf16 convert (all blocks) + plan (block 0) ----
// ws[0] = n_items; ws[1+i] = (fw<<8) | (mg<<4) | nvalid
__global__ __launch_bounds__(256) void qgen_prep(const float* __restrict__ x,
                                                 short* __restrict__ xbf,
                                                 const int* __restrict__ fwv,
                                                 int* __restrict__ ws) {
    const int tid = threadIdx.x;
    if (blockIdx.x == 0 && tid < 64) {
        const int v = fwv[tid];
        int nitems = 0;
        for (int fw = 0; fw < NFW; ++fw) {
            const unsigned long long m = __ballot(v == fw);
            if (tid == 0) {
                const int cnt = __popcll(m);
                for (int mg = 0; mg * 8 < cnt; ++mg) {
                    const int nv = min(8, cnt - mg * 8);
                    ws[1 + nitems] = (fw << 8) | (mg << 4) | nv;
                    ++nitems;
                }
            }
        }
        if (tid == 0) ws[0] = nitems;
    }
    const long i = ((long)blockIdx.x * 256 + tid) * 8;
    float4 a = *(const float4*)(x + i);
    float4 b = *(const float4*)(x + i + 4);
    s16x8 p = { f2bf(a.x), f2bf(a.y), f2bf(a.z), f2bf(a.w),
                f2bf(b.x), f2bf(b.y), f2bf(b.z), f2bf(b.w) };
    *(s16x8*)(xbf + i) = p;
}

// ---- standalone plan (fp32 fallback path, no convert) ----
__global__ void qgen_plan(const int* __restrict__ fwv, int* __restrict__ ws) {
    const int tid = threadIdx.x;   // 64 threads
    const int v = fwv[tid];
    int nitems = 0;
    for (int fw = 0; fw < NFW; ++fw) {
        const unsigned long long m = __ballot(v == fw);
        if (tid == 0) {
            const int cnt = __popcll(m);
            for (int mg = 0; mg * 8 < cnt; ++mg) {
                const int nv = min(8, cnt - mg * 8);
                ws[1 + nitems] = (fw << 8) | (mg << 4) | nv;
                ++nitems;
            }
        }
    }
    if (tid == 0) ws[0] = nitems;
}

template<int XB>
__global__ __launch_bounds__(512) void qgen_kernel(
    const float* __restrict__ x,      // [64][32][1024] fp32
    const short* __restrict__ xbf,    // [64][32][1024] bf16 (if XB)
    const int*   __restrict__ fwv,    // [64]
    const float* __restrict__ w,      // [16][1024][4096]
    const float* __restrict__ bias,   // [16][4096]
    const int*   __restrict__ ws,     // work list
    float*       __restrict__ out)    // [64][32][4096] flat
{
    const int tid = threadIdx.x;

    // ---- XCD-aware work decode (round-robin dispatch: bid%8 -> XCD) ----
    // Same-item blocks land 4-per-XCD, temporally adjacent -> X tile L2-hits.
    const int bid = blockIdx.x;
    const int xcd = bid & (NXCD - 1);
    const int jj  = bid >> 3;            // 0..87 within this XCD
    const int it  = jj >> 2;             // item index 0..21

    // ---- early exit BEFORE any heavy loads ----
    const int nitems = ws[0];
    if (it >= nitems) return;
    const int item   = ws[1 + it];
    const int myfw   = item >> 8;
    const int mg     = (item >> 4) & 15;
    const int nvalid = item & 15;         // 1..8
    const int ntile  = (xcd << 2) | (jj & 3);
    const int n0     = ntile * BN;

    __shared__ int   s_list[BATCH];
    __shared__ short XT[BM][XK];
    __shared__ short WT[BN][WK];

    // ---- W staging map: (col wn, k-16th wkh), column dword loads ----
    const int wn  = tid & 127;
    const int wkh = (tid >> 7) * 16;      // 4 groups x 16 k-rows
    const float* wsrc = w + (long)myfw * DIM * EOUT + (long)wkh * EOUT + n0 + wn;

    // ---- prologue: issue W loads for chunk 0 immediately ----
    float wreg[16];
    #pragma unroll
    for (int j = 0; j < 16; ++j) wreg[j] = wsrc[(long)j * EOUT];

    // ---- rebuild batch list for this fw (wave 0 ballot + rank) ----
    if (tid < 64) {
        const int myv = fwv[tid];
        const unsigned long long mask = __ballot(myv == myfw);
        if (myv == myfw) {
            const int rank = __popcll(mask & ((1ull << tid) - 1ull));
            s_list[rank] = tid;
        }
    }
    __syncthreads();

    // ---- X staging map: (row sm 0..255, k-half skb: 32 elems) ----
    const int  sm    = tid >> 1;
    const int  skb   = (tid & 1) * 32;
    const int  sslot = sm >> 5;           // 0..7
    const bool svalid = (sslot < nvalid);
    const long srow   = (svalid ? s_list[mg * 8 + sslot] : 0) * SEQ + (sm & 31);
    const float* xsrc32 = x   + srow * (long)DIM + skb;
    const short* xsrc16 = xbf + srow * (long)DIM + skb;

    // ---- prologue: issue X loads for chunk 0 ----
    s16x8  x16[4];
    float4 xv[8];
    if (XB) {
        if (svalid) {
            #pragma unroll
            for (int j = 0; j < 4; ++j)
                x16[j] = *(const s16x8*)(xsrc16 + 8 * j);
        }
    } else {
        if (svalid) {
            #pragma unroll
            for (int j = 0; j < 8; ++j) xv[j] = *(const float4*)(xsrc32 + 4 * j);
        }
    }

    // ---- wave / fragment geometry: 4x2 waves, each 64 rows x 64 cols ----
    const int wave  = tid >> 6;           // 0..7
    const int lane  = tid & 63;
    const int wm    = (wave >> 1) * 64;   // 0,64,128,192
    const int wncol = (wave & 1) * 64;    // 0,64
    const int lrow  = lane & 15;
    const int lk    = (lane >> 4) * 4;

    f32x4 acc[4][4];
    #pragma unroll
    for (int i = 0; i < 4; ++i)
        #pragma unroll
        for (int j = 0; j < 4; ++j)
            acc[i][j] = (f32x4){0.f, 0.f, 0.f, 0.f};

    // zero-fill invalid X rows once
    if (!svalid) {
        s16x4 z = {0, 0, 0, 0};
        #pragma unroll
        for (int j = 0; j < 8; ++j) *(s16x4*)&XT[sm][skb + 4 * j] = z;
    }

    for (int k0 = 0; k0 < DIM; k0 += BK) {
        __syncthreads();   // previous compute done reading LDS

        // (1) X -> LDS (regs prefetched a full iteration ago); b64 stores only
        if (svalid) {
            if (XB) {
                #pragma unroll
                for (int j = 0; j < 4; ++j) {
                    s16x4 lo = __builtin_shufflevector(x16[j], x16[j], 0, 1, 2, 3);
                    s16x4 hi = __builtin_shufflevector(x16[j], x16[j], 4, 5, 6, 7);
                    *(s16x4*)&XT[sm][skb + 8 * j]     = lo;
                    *(s16x4*)&XT[sm][skb + 8 * j + 4] = hi;
                }
            } else {
                #pragma unroll
                for (int j = 0; j < 8; ++j) {
                    s16x4 p = { f2bf(xv[j].x), f2bf(xv[j].y),
                                f2bf(xv[j].z), f2bf(xv[j].w) };
                    *(s16x4*)&XT[sm][skb + 4 * j] = p;
                }
            }
        }

        // (2) W: cvt + ds_write (wreg landed during previous MFMA phase)
        #pragma unroll
        for (int j = 0; j < 4; ++j) {
            s16x4 p = { f2bf(wreg[4*j]), f2bf(wreg[4*j+1]),
                        f2bf(wreg[4*j+2]), f2bf(wreg[4*j+3]) };
            *(s16x4*)&WT[wn][wkh + 4 * j] = p;
        }

        // (3) issue W + X loads for next chunk (in flight across MFMA phase)
        {
            const long k1 = (k0 + BK < DIM) ? (long)(k0 + BK) : 0;
            const float* pw = wsrc + k1 * EOUT;
            #pragma unroll
            for (int j = 0; j < 16; ++j) wreg[j] = pw[(long)j * EOUT];
            if (XB) {
                if (svalid) {
                    #pragma unroll
                    for (int j = 0; j < 4; ++j)
                        x16[j] = *(const s16x8*)(xsrc16 + k1 + 8 * j);
                }
            } else {
                if (svalid) {
                    const float* px = xsrc32 + k1;
                    #pragma unroll
                    for (int j = 0; j < 8; ++j) xv[j] = *(const float4*)(px + 4 * j);
                }
            }
        }

        __syncthreads();   // staging visible

        #pragma unroll
        for (int kk = 0; kk < BK; kk += 32) {
            s16x8 a[4], b[4];
            #pragma unroll
            for (int i = 0; i < 4; ++i) {
                const short* p = &XT[wm + i * 16 + lrow][kk + lk];
                s16x4 lo = *(const s16x4*)p;
                s16x4 hi = *(const s16x4*)(p + 16);
                a[i] = __builtin_shufflevector(lo, hi, 0, 1, 2, 3, 4, 5, 6, 7);
            }
            #pragma unroll
            for (int j = 0; j < 4; ++j) {
                const short* p = &WT[wncol + j * 16 + lrow][kk + lk];
                s16x4 lo = *(const s16x4*)p;
                s16x4 hi = *(const s16x4*)(p + 16);
                b[j] = __builtin_shufflevector(lo, hi, 0, 1, 2, 3, 4, 5, 6, 7);
            }
            #pragma unroll
            for (int i = 0; i < 4; ++i)
                #pragma unroll
                for (int j = 0; j < 4; ++j)
                    acc[i][j] = __builtin_amdgcn_mfma_f32_16x16x32_bf16(
                        a[i], b[j], acc[i][j], 0, 0, 0);
        }
    }

    // ---- epilogue: +bias, tanh, store ----
    int bidx[8];
    #pragma unroll
    for (int s = 0; s < 8; ++s) bidx[s] = (s < nvalid) ? s_list[mg * 8 + s] : -1;
    const float* bv = bias + (long)myfw * EOUT;

    #pragma unroll
    for (int i = 0; i < 4; ++i) {
        const int mbase = wm + i * 16 + (lane >> 4) * 4;
        #pragma unroll
        for (int j = 0; j < 4; ++j) {
            const int col = n0 + wncol + j * 16 + lrow;
            const float bb = bv[col];
            #pragma unroll
            for (int r = 0; r < 4; ++r) {
                const int m    = mbase + r;
                const int slot = m >> 5;
                const int b    = bidx[slot];
                if (b >= 0) {
                    float v = acc[i][j][r] + bb;
                    float e = __expf(2.0f * v);
                    float t = 1.0f - __fdividef(2.0f, e + 1.0f);
                    out[((long)(b * SEQ + (m & 31))) * EOUT + col] = t;
                }
            }
        }
    }
}

extern "C" void kernel_launch(void* const* d_in, const int* in_sizes, int n_in,
                              void* d_out, int out_size, void* d_ws, size_t ws_size,
                              hipStream_t stream) {
    const float* x    = (const float*)d_in[0];
    const int*   fwv  = (const int*)d_in[1];
    const float* w    = (const float*)d_in[2];
    const float* bias = (const float*)d_in[3];
    float* out = (float*)d_out;
    int*   ws  = (int*)d_ws;
    short* xbf = (short*)((char*)d_ws + 256);

    const size_t need = 256 + (size_t)BATCH * SEQ * DIM * 2;

    const int nblocks = (EOUT / BN) * MAX_ITEMS;   // 32 * 22 = 704, 1-D grid
    if (ws_size >= need) {
        qgen_prep<<<(BATCH * SEQ * DIM) / (256 * 8), 256, 0, stream>>>(x, xbf, fwv, ws);
        qgen_kernel<1><<<nblocks, 512, 0, stream>>>(x, xbf, fwv, w, bias, ws, out);
    } else {
        qgen_plan<<<1, 64, 0, stream>>>(fwv, ws);
        qgen_kernel<0><<<nblocks, 512, 0, stream>>>(x, xbf, fwv, w, bias, ws, out);
    }
}

// Round 9
// 85.457 us; speedup vs baseline: 1.0171x; 1.0171x over previous
//
#include <hip/hip_runtime.h>
#include <hip/hip_bf16.h>

#define BATCH 64
#define SEQ 32
#define DIM 1024
#define EOUT 4096
#define NFW 16

#define BM 256   // rows per block tile (8 batch-slots x 32 seq)
#define BN 128   // cols per block tile
#define BK 64    // k chunk
#define XK 68    // XT row stride: 17 dwords, odd -> conflict-free, 8B-aligned rows
#define WK 68    // WT row stride: same
#define MAX_ITEMS 22   // max sum ceil(cnt/8) = (64 + 16*7)/8 = 22
#define WS_HDR 1024    // bytes reserved for plan data before xbf

typedef float  f32x4 __attribute__((ext_vector_type(4)));
typedef short  s16x4 __attribute__((ext_vector_type(4)));
typedef short  s16x8 __attribute__((ext_vector_type(8)));

__device__ __forceinline__ short f2bf(float f) {
    union { float f; unsigned u; } v; v.f = f;
    unsigned r = v.u + 0x7fffu + ((v.u >> 16) & 1u);   // RNE
    return (short)(r >> 16);
}

// plan layout in ws (ints): [0]=nitems, [1+i]=(fw<<8)|nvalid, [32+i*8+s]=batch or -1
__device__ __forceinline__ void plan_body(int v, int tid, int* ws) {
    int nitems = 0;
    for (int fw = 0; fw < NFW; ++fw) {
        const unsigned long long m = __ballot(v == fw);
        if (tid == 0) {
            const int cnt = __popcll(m);
            unsigned long long mm = m;
            for (int mg = 0; mg * 8 < cnt; ++mg) {
                const int nv = min(8, cnt - mg * 8);
                ws[1 + nitems] = (fw << 8) | nv;
                #pragma unroll
                for (int s = 0; s < 8; ++s) {
                    int b = -1;
                    if (s < nv) { b = __ffsll((long long)mm) - 1; mm &= mm - 1; }
                    ws[32 + nitems * 8 + s] = b;
                }
                ++nitems;
            }
        }
    }
    if (tid == 0) ws[0] = nitems;
}

// ---- fused prep: X fp32->bf16 convert (all blocks) + plan (block 0) ----
__global__ __launch_bounds__(256) void qgen_prep(const float* __restrict__ x,
                                                 short* __restrict__ xbf,
                                                 const int* __restrict__ fwv,
                                                 int* __restrict__ ws) {
    const int tid = threadIdx.x;
    if (blockIdx.x == 0 && tid < 64) plan_body(fwv[tid], tid, ws);
    const long i = ((long)blockIdx.x * 256 + tid) * 8;
    float4 a = *(const float4*)(x + i);
    float4 b = *(const float4*)(x + i + 4);
    s16x8 p = { f2bf(a.x), f2bf(a.y), f2bf(a.z), f2bf(a.w),
                f2bf(b.x), f2bf(b.y), f2bf(b.z), f2bf(b.w) };
    *(s16x8*)(xbf + i) = p;
}

// ---- standalone plan (fp32 fallback path, no convert) ----
__global__ void qgen_plan(const int* __restrict__ fwv, int* __restrict__ ws) {
    const int tid = threadIdx.x;   // 64 threads
    plan_body(fwv[tid], tid, ws);
}

template<int XB>
__global__ __launch_bounds__(512) void qgen_kernel(
    const float* __restrict__ x,      // [64][32][1024] fp32
    const short* __restrict__ xbf,    // [64][32][1024] bf16 (if XB)
    const float* __restrict__ w,      // [16][1024][4096]
    const float* __restrict__ bias,   // [16][4096]
    const int*   __restrict__ ws,     // plan
    float*       __restrict__ out)    // [64][32][4096] flat
{
    const int tid = threadIdx.x;

    // ---- early exit BEFORE any heavy loads ----
    const int nitems = ws[0];
    const int it = blockIdx.y;
    if (it >= nitems) return;
    const int item   = ws[1 + it];
    const int myfw   = item >> 8;
    const int nvalid = item & 255;        // 1..8
    const int n0     = blockIdx.x * BN;
    const int* lst   = ws + 32 + it * 8;

    __shared__ short XT[BM][XK];          // 34816 B
    __shared__ short WT[BN][WK];          // 17408 B  (total 52224 B -> 3 blk/CU)

    // ---- W staging map: (col wn, k-16th wkh), column dword loads ----
    const int wn  = tid & 127;
    const int wkh = (tid >> 7) * 16;      // 4 groups x 16 k-rows
    const float* wsrc = w + (long)myfw * DIM * EOUT + (long)wkh * EOUT + n0 + wn;

    // ---- prologue: issue W loads for chunk 0 immediately ----
    float wreg[16];
    #pragma unroll
    for (int j = 0; j < 16; ++j) wreg[j] = wsrc[(long)j * EOUT];

    // ---- X staging map: (row sm 0..255, k-half skb: 32 elems) ----
    const int  sm    = tid >> 1;
    const int  skb   = (tid & 1) * 32;
    const int  sslot = sm >> 5;           // 0..7
    const bool svalid = (sslot < nvalid);
    const long srow   = (svalid ? lst[sslot] : 0) * (long)SEQ + (sm & 31);
    const float* xsrc32 = x   + srow * (long)DIM + skb;
    const short* xsrc16 = xbf + srow * (long)DIM + skb;

    // ---- prologue: issue X loads for chunk 0 ----
    s16x8  x16[4];
    float4 xv[8];
    if (XB) {
        if (svalid) {
            #pragma unroll
            for (int j = 0; j < 4; ++j)
                x16[j] = *(const s16x8*)(xsrc16 + 8 * j);
        }
    } else {
        if (svalid) {
            #pragma unroll
            for (int j = 0; j < 8; ++j) xv[j] = *(const float4*)(xsrc32 + 4 * j);
        }
    }

    // ---- wave / fragment geometry: 4x2 waves, each 64 rows x 64 cols ----
    const int wave  = tid >> 6;           // 0..7
    const int lane  = tid & 63;
    const int wm    = (wave >> 1) * 64;   // 0,64,128,192
    const int wncol = (wave & 1) * 64;    // 0,64
    const int lrow  = lane & 15;
    const int lk    = (lane >> 4) * 4;

    f32x4 acc[4][4];
    #pragma unroll
    for (int i = 0; i < 4; ++i)
        #pragma unroll
        for (int j = 0; j < 4; ++j)
            acc[i][j] = (f32x4){0.f, 0.f, 0.f, 0.f};

    // zero-fill invalid X rows once
    if (!svalid) {
        s16x4 z = {0, 0, 0, 0};
        #pragma unroll
        for (int j = 0; j < 8; ++j) *(s16x4*)&XT[sm][skb + 4 * j] = z;
    }

    for (int k0 = 0; k0 < DIM; k0 += BK) {
        __syncthreads();   // previous compute done reading LDS

        // (1) X -> LDS (regs prefetched a full iteration ago); b64 stores
        if (svalid) {
            if (XB) {
                #pragma unroll
                for (int j = 0; j < 4; ++j) {
                    s16x4 lo = __builtin_shufflevector(x16[j], x16[j], 0, 1, 2, 3);
                    s16x4 hi = __builtin_shufflevector(x16[j], x16[j], 4, 5, 6, 7);
                    *(s16x4*)&XT[sm][skb + 8 * j]     = lo;
                    *(s16x4*)&XT[sm][skb + 8 * j + 4] = hi;
                }
            } else {
                #pragma unroll
                for (int j = 0; j < 8; ++j) {
                    s16x4 p = { f2bf(xv[j].x), f2bf(xv[j].y),
                                f2bf(xv[j].z), f2bf(xv[j].w) };
                    *(s16x4*)&XT[sm][skb + 4 * j] = p;
                }
            }
        }

        // (2) W: cvt + ds_write (wreg landed during previous MFMA phase)
        #pragma unroll
        for (int j = 0; j < 4; ++j) {
            s16x4 p = { f2bf(wreg[4*j]), f2bf(wreg[4*j+1]),
                        f2bf(wreg[4*j+2]), f2bf(wreg[4*j+3]) };
            *(s16x4*)&WT[wn][wkh + 4 * j] = p;
        }

        // (3) issue W + X loads for next chunk (in flight across MFMA phase)
        {
            const long k1 = (k0 + BK < DIM) ? (long)(k0 + BK) : 0;
            const float* pw = wsrc + k1 * EOUT;
            #pragma unroll
            for (int j = 0; j < 16; ++j) wreg[j] = pw[(long)j * EOUT];
            if (XB) {
                if (svalid) {
                    #pragma unroll
                    for (int j = 0; j < 4; ++j)
                        x16[j] = *(const s16x8*)(xsrc16 + k1 + 8 * j);
                }
            } else {
                if (svalid) {
                    const float* px = xsrc32 + k1;
                    #pragma unroll
                    for (int j = 0; j < 8; ++j) xv[j] = *(const float4*)(px + 4 * j);
                }
            }
        }

        __syncthreads();   // staging visible

        #pragma unroll
        for (int kk = 0; kk < BK; kk += 32) {
            s16x8 a[4], b[4];
            #pragma unroll
            for (int i = 0; i < 4; ++i) {
                const short* p = &XT[wm + i * 16 + lrow][kk + lk];
                s16x4 lo = *(const s16x4*)p;
                s16x4 hi = *(const s16x4*)(p + 16);
                a[i] = __builtin_shufflevector(lo, hi, 0, 1, 2, 3, 4, 5, 6, 7);
            }
            #pragma unroll
            for (int j = 0; j < 4; ++j) {
                const short* p = &WT[wncol + j * 16 + lrow][kk + lk];
                s16x4 lo = *(const s16x4*)p;
                s16x4 hi = *(const s16x4*)(p + 16);
                b[j] = __builtin_shufflevector(lo, hi, 0, 1, 2, 3, 4, 5, 6, 7);
            }
            #pragma unroll
            for (int i = 0; i < 4; ++i)
                #pragma unroll
                for (int j = 0; j < 4; ++j)
                    acc[i][j] = __builtin_amdgcn_mfma_f32_16x16x32_bf16(
                        a[i], b[j], acc[i][j], 0, 0, 0);
        }
    }

    // ---- epilogue: +bias, tanh, store ----
    int bidx[8];
    #pragma unroll
    for (int s = 0; s < 8; ++s) bidx[s] = (s < nvalid) ? lst[s] : -1;
    const float* bv = bias + (long)myfw * EOUT;

    #pragma unroll
    for (int i = 0; i < 4; ++i) {
        const int mbase = wm + i * 16 + (lane >> 4) * 4;
        #pragma unroll
        for (int j = 0; j < 4; ++j) {
            const int col = n0 + wncol + j * 16 + lrow;
            const float bb = bv[col];
            #pragma unroll
            for (int r = 0; r < 4; ++r) {
                const int m    = mbase + r;
                const int slot = m >> 5;
                const int b    = bidx[slot];
                if (b >= 0) {
                    float v = acc[i][j][r] + bb;
                    float e = __expf(2.0f * v);
                    float t = 1.0f - __fdividef(2.0f, e + 1.0f);
                    out[((long)(b * SEQ + (m & 31))) * EOUT + col] = t;
                }
            }
        }
    }
}

extern "C" void kernel_launch(void* const* d_in, const int* in_sizes, int n_in,
                              void* d_out, int out_size, void* d_ws, size_t ws_size,
                              hipStream_t stream) {
    const float* x    = (const float*)d_in[0];
    const int*   fwv  = (const int*)d_in[1];
    const float* w    = (const float*)d_in[2];
    const float* bias = (const float*)d_in[3];
    float* out = (float*)d_out;
    int*   ws  = (int*)d_ws;
    short* xbf = (short*)((char*)d_ws + WS_HDR);

    const size_t need = WS_HDR + (size_t)BATCH * SEQ * DIM * 2;

    dim3 grid(EOUT / BN, MAX_ITEMS, 1);   // (32, 22)
    if (ws_size >= need) {
        qgen_prep<<<(BATCH * SEQ * DIM) / (256 * 8), 256, 0, stream>>>(x, xbf, fwv, ws);
        qgen_kernel<1><<<grid, 512, 0, stream>>>(x, xbf, w, bias, ws, out);
    } else {
        qgen_plan<<<1, 64, 0, stream>>>(fwv, ws);
        qgen_kernel<0><<<grid, 512, 0, stream>>>(x, xbf, w, bias, ws, out);
    }
}

// Round 10
// 83.002 us; speedup vs baseline: 1.0472x; 1.0296x over previous
//
#include <hip/hip_runtime.h>
#include <hip/hip_bf16.h>

#define BATCH 64
#define SEQ 32
#define DIM 1024
#define EOUT 4096
#define NFW 16

#define BM 256   // rows per block tile (8 batch-slots x 32 seq)
#define BN 256   // cols per block tile (halves X re-read vs BN=128)
#define BK 64    // k chunk
#define XK 68    // XT row stride: measured conflict-free (R3/R7: SQ_LDS_BANK_CONFLICT=0)
#define WK 68    // WT row stride: same
#define MAX_ITEMS 22   // max sum ceil(cnt/8) = (64 + 16*7)/8 = 22
#define WS_HDR 1024    // bytes reserved for plan data before xbf

typedef float  f32x4 __attribute__((ext_vector_type(4)));
typedef short  s16x4 __attribute__((ext_vector_type(4)));
typedef short  s16x8 __attribute__((ext_vector_type(8)));

__device__ __forceinline__ short f2bf(float f) {
    union { float f; unsigned u; } v; v.f = f;
    unsigned r = v.u + 0x7fffu + ((v.u >> 16) & 1u);   // RNE
    return (short)(r >> 16);
}

// plan layout in ws (ints): [0]=nitems, [1+i]=(fw<<8)|nvalid, [32+i*8+s]=batch or -1
__device__ __forceinline__ void plan_body(int v, int tid, int* ws) {
    int nitems = 0;
    for (int fw = 0; fw < NFW; ++fw) {
        const unsigned long long m = __ballot(v == fw);
        if (tid == 0) {
            const int cnt = __popcll(m);
            unsigned long long mm = m;
            for (int mg = 0; mg * 8 < cnt; ++mg) {
                const int nv = min(8, cnt - mg * 8);
                ws[1 + nitems] = (fw << 8) | nv;
                #pragma unroll
                for (int s = 0; s < 8; ++s) {
                    int b = -1;
                    if (s < nv) { b = __ffsll((long long)mm) - 1; mm &= mm - 1; }
                    ws[32 + nitems * 8 + s] = b;
                }
                ++nitems;
            }
        }
    }
    if (tid == 0) ws[0] = nitems;
}

// ---- fused prep: X fp32->bf16 convert (all blocks) + plan (block 0) ----
__global__ __launch_bounds__(256) void qgen_prep(const float* __restrict__ x,
                                                 short* __restrict__ xbf,
                                                 const int* __restrict__ fwv,
                                                 int* __restrict__ ws) {
    const int tid = threadIdx.x;
    if (blockIdx.x == 0 && tid < 64) plan_body(fwv[tid], tid, ws);
    const long i = ((long)blockIdx.x * 256 + tid) * 8;
    float4 a = *(const float4*)(x + i);
    float4 b = *(const float4*)(x + i + 4);
    s16x8 p = { f2bf(a.x), f2bf(a.y), f2bf(a.z), f2bf(a.w),
                f2bf(b.x), f2bf(b.y), f2bf(b.z), f2bf(b.w) };
    *(s16x8*)(xbf + i) = p;
}

// ---- standalone plan (fp32 fallback path, no convert) ----
__global__ void qgen_plan(const int* __restrict__ fwv, int* __restrict__ ws) {
    const int tid = threadIdx.x;   // 64 threads
    plan_body(fwv[tid], tid, ws);
}

template<int XB>
__global__ __launch_bounds__(512) void qgen_kernel(
    const float* __restrict__ x,      // [64][32][1024] fp32
    const short* __restrict__ xbf,    // [64][32][1024] bf16 (if XB)
    const float* __restrict__ w,      // [16][1024][4096]
    const float* __restrict__ bias,   // [16][4096]
    const int*   __restrict__ ws,     // plan
    float*       __restrict__ out)    // [64][32][4096] flat
{
    const int tid = threadIdx.x;

    // ---- early exit BEFORE any heavy loads ----
    const int nitems = ws[0];
    const int it = blockIdx.y;
    if (it >= nitems) return;
    const int item   = ws[1 + it];
    const int myfw   = item >> 8;
    const int nvalid = item & 255;        // 1..8
    const int n0     = blockIdx.x * BN;
    const int* lst   = ws + 32 + it * 8;

    __shared__ short XT[BM][XK];          // 34816 B
    __shared__ short WT[BN][WK];          // 34816 B (total 69632 -> 2 blk/CU)

    // ---- W staging map: (col wn 0..255, k-group wkh), column dword loads ----
    const int wn  = tid & 255;
    const int wkh = (tid >> 8) * 32;      // 2 groups x 32 k-rows
    const float* wsrc = w + (long)myfw * DIM * EOUT + (long)wkh * EOUT + n0 + wn;

    // ---- prologue: issue W loads for chunk 0 immediately ----
    float wreg[32];
    #pragma unroll
    for (int j = 0; j < 32; ++j) wreg[j] = wsrc[(long)j * EOUT];

    // ---- X staging map: (row sm 0..255, k-half skb: 32 elems) ----
    const int  sm    = tid >> 1;
    const int  skb   = (tid & 1) * 32;
    const int  sslot = sm >> 5;           // 0..7
    const bool svalid = (sslot < nvalid);
    const long srow   = (svalid ? lst[sslot] : 0) * (long)SEQ + (sm & 31);
    const float* xsrc32 = x   + srow * (long)DIM + skb;
    const short* xsrc16 = xbf + srow * (long)DIM + skb;

    // ---- prologue: issue X loads for chunk 0 ----
    s16x8  x16[4];
    float4 xv[8];
    if (XB) {
        if (svalid) {
            #pragma unroll
            for (int j = 0; j < 4; ++j)
                x16[j] = *(const s16x8*)(xsrc16 + 8 * j);
        }
    } else {
        if (svalid) {
            #pragma unroll
            for (int j = 0; j < 8; ++j) xv[j] = *(const float4*)(xsrc32 + 4 * j);
        }
    }

    // ---- wave / fragment geometry: 4x2 waves, each 64 rows x 128 cols ----
    const int wave  = tid >> 6;           // 0..7
    const int lane  = tid & 63;
    const int wm    = (wave >> 1) * 64;   // 0,64,128,192
    const int wncol = (wave & 1) * 128;   // 0,128
    const int lrow  = lane & 15;
    const int lk    = (lane >> 4) * 4;

    f32x4 acc[4][8];
    #pragma unroll
    for (int i = 0; i < 4; ++i)
        #pragma unroll
        for (int j = 0; j < 8; ++j)
            acc[i][j] = (f32x4){0.f, 0.f, 0.f, 0.f};

    // zero-fill invalid X rows once
    if (!svalid) {
        s16x4 z = {0, 0, 0, 0};
        #pragma unroll
        for (int j = 0; j < 8; ++j) *(s16x4*)&XT[sm][skb + 4 * j] = z;
    }

    for (int k0 = 0; k0 < DIM; k0 += BK) {
        __syncthreads();   // previous compute done reading LDS

        // (1) X -> LDS (regs prefetched a full iteration ago); b64 stores
        if (svalid) {
            if (XB) {
                #pragma unroll
                for (int j = 0; j < 4; ++j) {
                    s16x4 lo = __builtin_shufflevector(x16[j], x16[j], 0, 1, 2, 3);
                    s16x4 hi = __builtin_shufflevector(x16[j], x16[j], 4, 5, 6, 7);
                    *(s16x4*)&XT[sm][skb + 8 * j]     = lo;
                    *(s16x4*)&XT[sm][skb + 8 * j + 4] = hi;
                }
            } else {
                #pragma unroll
                for (int j = 0; j < 8; ++j) {
                    s16x4 p = { f2bf(xv[j].x), f2bf(xv[j].y),
                                f2bf(xv[j].z), f2bf(xv[j].w) };
                    *(s16x4*)&XT[sm][skb + 4 * j] = p;
                }
            }
        }

        // (2) W: cvt + ds_write (wreg landed during previous MFMA phase)
        #pragma unroll
        for (int j = 0; j < 8; ++j) {
            s16x4 p = { f2bf(wreg[4*j]), f2bf(wreg[4*j+1]),
                        f2bf(wreg[4*j+2]), f2bf(wreg[4*j+3]) };
            *(s16x4*)&WT[wn][wkh + 4 * j] = p;
        }

        // (3) issue W + X loads for next chunk (in flight across MFMA phase)
        {
            const long k1 = (k0 + BK < DIM) ? (long)(k0 + BK) : 0;
            const float* pw = wsrc + k1 * EOUT;
            #pragma unroll
            for (int j = 0; j < 32; ++j) wreg[j] = pw[(long)j * EOUT];
            if (XB) {
                if (svalid) {
                    #pragma unroll
                    for (int j = 0; j < 4; ++j)
                        x16[j] = *(const s16x8*)(xsrc16 + k1 + 8 * j);
                }
            } else {
                if (svalid) {
                    const float* px = xsrc32 + k1;
                    #pragma unroll
                    for (int j = 0; j < 8; ++j) xv[j] = *(const float4*)(px + 4 * j);
                }
            }
        }

        __syncthreads();   // staging visible

        #pragma unroll
        for (int kk = 0; kk < BK; kk += 32) {
            s16x8 a[4], b[8];
            #pragma unroll
            for (int i = 0; i < 4; ++i) {
                const short* p = &XT[wm + i * 16 + lrow][kk + lk];
                s16x4 lo = *(const s16x4*)p;
                s16x4 hi = *(const s16x4*)(p + 16);
                a[i] = __builtin_shufflevector(lo, hi, 0, 1, 2, 3, 4, 5, 6, 7);
            }
            #pragma unroll
            for (int j = 0; j < 8; ++j) {
                const short* p = &WT[wncol + j * 16 + lrow][kk + lk];
                s16x4 lo = *(const s16x4*)p;
                s16x4 hi = *(const s16x4*)(p + 16);
                b[j] = __builtin_shufflevector(lo, hi, 0, 1, 2, 3, 4, 5, 6, 7);
            }
            #pragma unroll
            for (int i = 0; i < 4; ++i)
                #pragma unroll
                for (int j = 0; j < 8; ++j)
                    acc[i][j] = __builtin_amdgcn_mfma_f32_16x16x32_bf16(
                        a[i], b[j], acc[i][j], 0, 0, 0);
        }
    }

    // ---- epilogue: +bias, tanh, store ----
    int bidx[8];
    #pragma unroll
    for (int s = 0; s < 8; ++s) bidx[s] = (s < nvalid) ? lst[s] : -1;
    const float* bv = bias + (long)myfw * EOUT;

    #pragma unroll
    for (int i = 0; i < 4; ++i) {
        const int mbase = wm + i * 16 + (lane >> 4) * 4;
        #pragma unroll
        for (int j = 0; j < 8; ++j) {
            const int col = n0 + wncol + j * 16 + lrow;
            const float bb = bv[col];
            #pragma unroll
            for (int r = 0; r < 4; ++r) {
                const int m    = mbase + r;
                const int slot = m >> 5;
                const int b    = bidx[slot];
                if (b >= 0) {
                    float v = acc[i][j][r] + bb;
                    float e = __expf(2.0f * v);
                    float t = 1.0f - __fdividef(2.0f, e + 1.0f);
                    out[((long)(b * SEQ + (m & 31))) * EOUT + col] = t;
                }
            }
        }
    }
}

extern "C" void kernel_launch(void* const* d_in, const int* in_sizes, int n_in,
                              void* d_out, int out_size, void* d_ws, size_t ws_size,
                              hipStream_t stream) {
    const float* x    = (const float*)d_in[0];
    const int*   fwv  = (const int*)d_in[1];
    const float* w    = (const float*)d_in[2];
    const float* bias = (const float*)d_in[3];
    float* out = (float*)d_out;
    int*   ws  = (int*)d_ws;
    short* xbf = (short*)((char*)d_ws + WS_HDR);

    const size_t need = WS_HDR + (size_t)BATCH * SEQ * DIM * 2;

    dim3 grid(EOUT / BN, MAX_ITEMS, 1);   // (16, 22)
    if (ws_size >= need) {
        qgen_prep<<<(BATCH * SEQ * DIM) / (256 * 8), 256, 0, stream>>>(x, xbf, fwv, ws);
        qgen_kernel<1><<<grid, 512, 0, stream>>>(x, xbf, w, bias, ws, out);
    } else {
        qgen_plan<<<1, 64, 0, stream>>>(fwv, ws);
        qgen_kernel<0><<<grid, 512, 0, stream>>>(x, xbf, w, bias, ws, out);
    }
}